// Round 1
// baseline (669.141 us; speedup 1.0000x reference)
//
#include <hip/hip_runtime.h>

typedef unsigned short u16;
typedef __bf16 bf16x8 __attribute__((ext_vector_type(8)));
typedef float f32x4 __attribute__((ext_vector_type(4)));
typedef u16 u16x8 __attribute__((ext_vector_type(8)));

static constexpr int Bb = 4, Ss = 2048, Dd = 1024, Hh = 16, DKk = 64;
static constexpr int Mg = Bb * Ss;   // 8192
static constexpr int Kg = Dd;        // 1024
static constexpr int Ng = Dd;        // 1024

__device__ __forceinline__ u16 f2b(float f) {
    union { float f; unsigned int u; } x; x.f = f;
    unsigned int r = x.u + 0x7FFFu + ((x.u >> 16) & 1u);
    return (u16)(r >> 16);
}

// ---------------------------------------------------------------------------
// Weight transpose + convert: W f32 [1024][1024] row-major -> Wt bf16 [n][k]
// 64x64 tiles through LDS so both global read and write are coalesced.
// ---------------------------------------------------------------------------
__global__ __launch_bounds__(256) void wt_kernel(const float* __restrict__ W,
                                                 u16* __restrict__ Wt) {
    __shared__ __attribute__((aligned(16))) u16 T[64 * 72];
    const int k0 = blockIdx.x * 64, n0 = blockIdx.y * 64;
    const int tid = threadIdx.x;
    // load 64 rows (k) x 64 cols (n): 64*16 float4 chunks, 4 per thread
    for (int i = 0; i < 4; ++i) {
        int flat = tid + i * 256;
        int r = flat >> 4, c4 = flat & 15;
        float4 w4 = *(const float4*)(W + (size_t)(k0 + r) * 1024 + n0 + c4 * 4);
        u16* d = &T[r * 72 + c4 * 4];
        d[0] = f2b(w4.x); d[1] = f2b(w4.y); d[2] = f2b(w4.z); d[3] = f2b(w4.w);
    }
    __syncthreads();
    // write transposed: 64 rows (n) x 8 chunks of 8 bf16 (k), 2 per thread
    for (int i = 0; i < 2; ++i) {
        int flat = tid + i * 256;
        int n = flat >> 3, c8 = flat & 7;
        u16x8 v;
        for (int jj = 0; jj < 8; ++jj) v[jj] = T[(c8 * 8 + jj) * 72 + n];
        *(u16x8*)(Wt + (size_t)(n0 + n) * 1024 + k0 + c8 * 8) = v;
    }
}

// ---------------------------------------------------------------------------
// GEMM: C[M=8192][N=1024] = A[M][K=1024] @ B[K][N] + bias
//   B is supplied pre-transposed bf16: Bt[n][k].
//   MODE 0: A is f32 (convert inline), output bf16 head-split [b,h,s,dk]
//   MODE 1: A is bf16, output f32 plain [m][n]
// 128x128 tile, BK=32, 4 waves (2x2), each wave 4x4 MFMA tiles of 16x16x32.
// ---------------------------------------------------------------------------
template <int MODE>
__global__ __launch_bounds__(256) void gemm_kernel(const void* __restrict__ Aptr,
                                                   const u16* __restrict__ Bt,
                                                   const float* __restrict__ bias,
                                                   void* __restrict__ Out) {
    __shared__ __attribute__((aligned(16))) u16 As[128 * 40];  // stride 40 (pad 8)
    __shared__ __attribute__((aligned(16))) u16 Bs[128 * 40];
    const int tid = threadIdx.x;
    const int wave = tid >> 6, lane = tid & 63;
    const int quad = lane >> 4, l15 = lane & 15;
    const int m0 = blockIdx.x * 128, n0 = blockIdx.y * 128;
    const int wm = (wave >> 1) * 64, wn = (wave & 1) * 64;

    f32x4 acc[4][4] = {};

    for (int k0 = 0; k0 < Kg; k0 += 32) {
        __syncthreads();
        if (MODE == 0) {
            const float* A = (const float*)Aptr;
            for (int i = 0; i < 4; ++i) {
                int flat = tid + i * 256;          // 128 rows x 8 float4
                int r = flat >> 3, c4 = flat & 7;
                float4 a4 = *(const float4*)(A + (size_t)(m0 + r) * Kg + k0 + c4 * 4);
                u16* d = &As[r * 40 + c4 * 4];
                d[0] = f2b(a4.x); d[1] = f2b(a4.y); d[2] = f2b(a4.z); d[3] = f2b(a4.w);
            }
        } else {
            const u16* A = (const u16*)Aptr;
            for (int i = 0; i < 2; ++i) {
                int flat = tid + i * 256;          // 128 rows x 4 chunks of 8 bf16
                int r = flat >> 2, c8 = flat & 3;
                u16x8 a8 = *(const u16x8*)(A + (size_t)(m0 + r) * Kg + k0 + c8 * 8);
                *(u16x8*)(&As[r * 40 + c8 * 8]) = a8;
            }
        }
        for (int i = 0; i < 2; ++i) {
            int flat = tid + i * 256;              // 128 n-rows x 4 chunks of 8
            int r = flat >> 2, c8 = flat & 3;
            u16x8 b8 = *(const u16x8*)(Bt + (size_t)(n0 + r) * Kg + k0 + c8 * 8);
            *(u16x8*)(&Bs[r * 40 + c8 * 8]) = b8;
        }
        __syncthreads();

        bf16x8 a[4], b[4];
        for (int i = 0; i < 4; ++i)
            a[i] = *(const bf16x8*)(&As[(wm + i * 16 + l15) * 40 + quad * 8]);
        for (int j = 0; j < 4; ++j)
            b[j] = *(const bf16x8*)(&Bs[(wn + j * 16 + l15) * 40 + quad * 8]);
        for (int i = 0; i < 4; ++i)
            for (int j = 0; j < 4; ++j)
                acc[i][j] = __builtin_amdgcn_mfma_f32_16x16x32_bf16(a[i], b[j], acc[i][j], 0, 0, 0);
    }

    for (int i = 0; i < 4; ++i) {
        for (int j = 0; j < 4; ++j) {
            int col = n0 + wn + j * 16 + l15;
            float bv = bias[col];
            for (int r = 0; r < 4; ++r) {
                int row = m0 + wm + i * 16 + quad * 4 + r;
                float v = acc[i][j][r] + bv;
                if (MODE == 0) {
                    int bb = row >> 11, s = row & 2047;
                    int h = col >> 6, dk = col & 63;
                    ((u16*)Out)[((((size_t)bb * Hh + h) * Ss) + s) * DKk + dk] = f2b(v);
                } else {
                    ((float*)Out)[(size_t)row * Ng + col] = v;
                }
            }
        }
    }
}

// ---------------------------------------------------------------------------
// Causal flash attention. Q/K/V bf16 [b,h,s,dk]. One block = 64 Q-rows x one
// (b,h). 4 waves; wave w owns Q rows [w*16, w*16+16). Online softmax.
// Output O bf16 [b,s,h,dk] (== plain [m][k] for the final projection GEMM).
// ---------------------------------------------------------------------------
__global__ __launch_bounds__(256) void attn_kernel(const u16* __restrict__ Qw,
                                                   const u16* __restrict__ Kw,
                                                   const u16* __restrict__ Vw,
                                                   u16* __restrict__ Ow) {
    __shared__ __attribute__((aligned(16))) u16 Qs[64 * 72];
    __shared__ __attribute__((aligned(16))) u16 Ks[64 * 72];
    __shared__ __attribute__((aligned(16))) u16 Vt[64 * 72];   // transposed: [d][kk]
    __shared__ __attribute__((aligned(16))) u16 Ps[4 * 16 * 72];

    const int qt = blockIdx.x, bh = blockIdx.y;
    const int q0 = qt * 64;
    const int tid = threadIdx.x, wave = tid >> 6, lane = tid & 63;
    const int quad = lane >> 4, l15 = lane & 15;
    const u16* Qb = Qw + (size_t)bh * Ss * DKk;
    const u16* Kb = Kw + (size_t)bh * Ss * DKk;
    const u16* Vb = Vw + (size_t)bh * Ss * DKk;

    // Q tile: 64 rows x 64 cols, 16B chunks (8 per row)
    for (int i = 0; i < 2; ++i) {
        int flat = tid + i * 256;
        int r = flat >> 3, c = flat & 7;
        u16x8 v = *(const u16x8*)(Qb + (size_t)(q0 + r) * DKk + c * 8);
        *(u16x8*)(&Qs[r * 72 + c * 8]) = v;
    }

    f32x4 acc_o[4] = {};
    float m_r[4], l_r[4];
    int rowg[4];
    for (int r = 0; r < 4; ++r) {
        m_r[r] = -1e30f; l_r[r] = 0.f;
        rowg[r] = q0 + wave * 16 + quad * 4 + r;
    }

    for (int j = 0; j <= qt; ++j) {
        __syncthreads();   // prior PV reads of Ks/Vt done before restaging
        for (int i = 0; i < 2; ++i) {
            int flat = tid + i * 256;
            int r = flat >> 3, c = flat & 7;
            u16x8 v = *(const u16x8*)(Kb + (size_t)(j * 64 + r) * DKk + c * 8);
            *(u16x8*)(&Ks[r * 72 + c * 8]) = v;
        }
        for (int i = 0; i < 2; ++i) {
            int flat = tid + i * 256;
            int r = flat >> 3, c = flat & 7;
            u16x8 v = *(const u16x8*)(Vb + (size_t)(j * 64 + r) * DKk + c * 8);
            for (int jj = 0; jj < 8; ++jj) Vt[(c * 8 + jj) * 72 + r] = v[jj];
        }
        __syncthreads();

        // S = Q K^T  (wave's 16 rows x 64 cols, DK=64 -> 2 MFMA per col-tile)
        bf16x8 aq0 = *(const bf16x8*)(&Qs[(wave * 16 + l15) * 72 + quad * 8]);
        bf16x8 aq1 = *(const bf16x8*)(&Qs[(wave * 16 + l15) * 72 + 32 + quad * 8]);
        f32x4 sacc[4];
        for (int ct = 0; ct < 4; ++ct) {
            bf16x8 bk0 = *(const bf16x8*)(&Ks[(ct * 16 + l15) * 72 + quad * 8]);
            bf16x8 bk1 = *(const bf16x8*)(&Ks[(ct * 16 + l15) * 72 + 32 + quad * 8]);
            f32x4 z = {};
            z = __builtin_amdgcn_mfma_f32_16x16x32_bf16(aq0, bk0, z, 0, 0, 0);
            z = __builtin_amdgcn_mfma_f32_16x16x32_bf16(aq1, bk1, z, 0, 0, 0);
            sacc[ct] = z;
        }

        // scale + causal mask + online softmax (row stats across 16 lanes)
        float mnew[4], alpha[4];
        for (int r = 0; r < 4; ++r) {
            float mx = -1e30f;
            for (int ct = 0; ct < 4; ++ct) {
                float s = sacc[ct][r] * 0.125f;
                int ck = j * 64 + ct * 16 + l15;
                if (ck > rowg[r]) s = -1e30f;
                sacc[ct][r] = s;
                mx = fmaxf(mx, s);
            }
            for (int off = 1; off < 16; off <<= 1)
                mx = fmaxf(mx, __shfl_xor(mx, off, 64));
            mnew[r] = fmaxf(m_r[r], mx);
        }
        for (int r = 0; r < 4; ++r) {
            alpha[r] = __expf(m_r[r] - mnew[r]);
            float sum = 0.f;
            for (int ct = 0; ct < 4; ++ct) {
                float p = __expf(sacc[ct][r] - mnew[r]);
                sacc[ct][r] = p;
                sum += p;
            }
            for (int off = 1; off < 16; off <<= 1)
                sum += __shfl_xor(sum, off, 64);
            l_r[r] = l_r[r] * alpha[r] + sum;
            m_r[r] = mnew[r];
        }
        for (int dt = 0; dt < 4; ++dt)
            for (int r = 0; r < 4; ++r) acc_o[dt][r] *= alpha[r];

        // P (C-layout) -> LDS -> A-layout for PV. Per-wave buffer, no barrier.
        u16* Pw = &Ps[wave * 16 * 72];
        for (int ct = 0; ct < 4; ++ct)
            for (int r = 0; r < 4; ++r)
                Pw[(quad * 4 + r) * 72 + ct * 16 + l15] = f2b(sacc[ct][r]);

        for (int kc = 0; kc < 2; ++kc) {
            bf16x8 ap = *(const bf16x8*)(&Pw[l15 * 72 + kc * 32 + quad * 8]);
            for (int dt = 0; dt < 4; ++dt) {
                bf16x8 bv = *(const bf16x8*)(&Vt[(dt * 16 + l15) * 72 + kc * 32 + quad * 8]);
                acc_o[dt] = __builtin_amdgcn_mfma_f32_16x16x32_bf16(ap, bv, acc_o[dt], 0, 0, 0);
            }
        }
    }

    const int b = bh >> 4, h = bh & 15;
    for (int r = 0; r < 4; ++r) {
        float inv = 1.f / l_r[r];
        int s = q0 + wave * 16 + quad * 4 + r;
        for (int dt = 0; dt < 4; ++dt) {
            int dk = dt * 16 + l15;
            Ow[(((size_t)b * Ss + s) * Hh + h) * DKk + dk] = f2b(acc_o[dt][r] * inv);
        }
    }
}

// ---------------------------------------------------------------------------
extern "C" void kernel_launch(void* const* d_in, const int* in_sizes, int n_in,
                              void* d_out, int out_size, void* d_ws, size_t ws_size,
                              hipStream_t stream) {
    // inputs: 0=x 1=q 2=k 3=v 4=mask 5=wq 6=bq 7=wk 8=bk 9=wv 10=bv 11=wo 12=bo
    const float* q  = (const float*)d_in[1];
    const float* k  = (const float*)d_in[2];
    const float* v  = (const float*)d_in[3];
    const float* wq = (const float*)d_in[5];
    const float* bq = (const float*)d_in[6];
    const float* wk = (const float*)d_in[7];
    const float* bk = (const float*)d_in[8];
    const float* wv = (const float*)d_in[9];
    const float* bv = (const float*)d_in[10];
    const float* wo = (const float*)d_in[11];
    const float* bo = (const float*)d_in[12];
    float* out = (float*)d_out;

    // workspace layout (bytes): 4 x 2MB transposed weights, 4 x 16MB bf16 tensors
    u16* WqT = (u16*)d_ws;
    u16* WkT = WqT + 1024 * 1024;
    u16* WvT = WkT + 1024 * 1024;
    u16* WoT = WvT + 1024 * 1024;
    u16* Qw  = WoT + 1024 * 1024;
    u16* Kw  = Qw + (size_t)Mg * Kg;
    u16* Vw  = Kw + (size_t)Mg * Kg;
    u16* Ow  = Vw + (size_t)Mg * Kg;

    dim3 wt_grid(16, 16);
    wt_kernel<<<wt_grid, 256, 0, stream>>>(wq, WqT);
    wt_kernel<<<wt_grid, 256, 0, stream>>>(wk, WkT);
    wt_kernel<<<wt_grid, 256, 0, stream>>>(wv, WvT);
    wt_kernel<<<wt_grid, 256, 0, stream>>>(wo, WoT);

    dim3 gg(Mg / 128, Ng / 128);
    gemm_kernel<0><<<gg, 256, 0, stream>>>(q, WqT, bq, Qw);
    gemm_kernel<0><<<gg, 256, 0, stream>>>(k, WkT, bk, Kw);
    gemm_kernel<0><<<gg, 256, 0, stream>>>(v, WvT, bv, Vw);

    dim3 ag(Ss / 64, Bb * Hh);
    attn_kernel<<<ag, 256, 0, stream>>>(Qw, Kw, Vw, Ow);

    gemm_kernel<1><<<gg, 256, 0, stream>>>(Ow, WoT, bo, out);
}

// Round 2
// 406.778 us; speedup vs baseline: 1.6450x; 1.6450x over previous
//
#include <hip/hip_runtime.h>

typedef unsigned short u16;
typedef __bf16 bf16x8 __attribute__((ext_vector_type(8)));
typedef float f32x4 __attribute__((ext_vector_type(4)));
typedef u16 u16x8 __attribute__((ext_vector_type(8)));
typedef u16 u16x4 __attribute__((ext_vector_type(4)));

static constexpr int Bb = 4, Ss = 2048, Dd = 1024, Hh = 16, DKk = 64;
static constexpr int Mg = Bb * Ss;   // 8192
static constexpr int Kg = Dd;        // 1024
static constexpr int Ng = Dd;        // 1024

#if __has_builtin(__builtin_amdgcn_exp2f)
#define EXP2 __builtin_amdgcn_exp2f
#else
#define EXP2 exp2f
#endif

__device__ __forceinline__ u16 f2b(float f) {
    union { __bf16 h; u16 u; } c; c.h = (__bf16)f; return c.u;
}

typedef const __attribute__((address_space(1))) void gas_t;
typedef __attribute__((address_space(3))) void las_t;
__device__ __forceinline__ void gll16(const void* g, void* l) {
    __builtin_amdgcn_global_load_lds((gas_t*)g, (las_t*)l, 16, 0, 0);
}

// ---------------------------------------------------------------------------
// f32 -> bf16 convert for q,k,v (one fused launch). 8 elems / thread.
// ---------------------------------------------------------------------------
__global__ __launch_bounds__(256) void conv3_kernel(const float* __restrict__ q,
                                                    const float* __restrict__ k,
                                                    const float* __restrict__ v,
                                                    u16* __restrict__ oq,
                                                    u16* __restrict__ ok,
                                                    u16* __restrict__ ov) {
    const size_t per = (size_t)Mg * Kg / 8;            // 1,048,576 chunks/tensor
    size_t id = (size_t)blockIdx.x * 256 + threadIdx.x;
    size_t t = id / per, off = (id % per) * 8;
    const float* src = (t == 0) ? q : (t == 1) ? k : v;
    u16* dst = (t == 0) ? oq : (t == 1) ? ok : ov;
    float4 a = *(const float4*)(src + off);
    float4 b = *(const float4*)(src + off + 4);
    u16x8 o;
    o[0] = f2b(a.x); o[1] = f2b(a.y); o[2] = f2b(a.z); o[3] = f2b(a.w);
    o[4] = f2b(b.x); o[5] = f2b(b.y); o[6] = f2b(b.z); o[7] = f2b(b.w);
    *(u16x8*)(dst + off) = o;
}

// ---------------------------------------------------------------------------
// Weight transpose+convert: 4 weights in one launch (blockIdx.z selects).
// W f32 [k][n] -> Wt bf16 [n][k].
// ---------------------------------------------------------------------------
__global__ __launch_bounds__(256) void wt4_kernel(const float* w0, const float* w1,
                                                  const float* w2, const float* w3,
                                                  u16* t0, u16* t1, u16* t2, u16* t3) {
    const float* W; u16* Wt;
    switch (blockIdx.z) {
        case 0: W = w0; Wt = t0; break;
        case 1: W = w1; Wt = t1; break;
        case 2: W = w2; Wt = t2; break;
        default: W = w3; Wt = t3; break;
    }
    __shared__ __attribute__((aligned(16))) u16 T[64 * 72];
    const int k0 = blockIdx.x * 64, n0 = blockIdx.y * 64;
    const int tid = threadIdx.x;
    for (int i = 0; i < 4; ++i) {
        int flat = tid + i * 256;
        int r = flat >> 4, c4 = flat & 15;
        float4 w4 = *(const float4*)(W + (size_t)(k0 + r) * 1024 + n0 + c4 * 4);
        u16* d = &T[r * 72 + c4 * 4];
        d[0] = f2b(w4.x); d[1] = f2b(w4.y); d[2] = f2b(w4.z); d[3] = f2b(w4.w);
    }
    __syncthreads();
    for (int i = 0; i < 2; ++i) {
        int flat = tid + i * 256;
        int n = flat >> 3, c8 = flat & 7;
        u16x8 v;
        for (int jj = 0; jj < 8; ++jj) v[jj] = T[(c8 * 8 + jj) * 72 + n];
        *(u16x8*)(Wt + (size_t)(n0 + n) * 1024 + k0 + c8 * 8) = v;
    }
}

// ---------------------------------------------------------------------------
// GEMM (m97-style): C[8192][1024] = A@B + bias.  A bf16 [m][k], Bt bf16 [n][k].
// 128x128 tile, BK=32, global_load_lds width-16 staging, unpadded stride-32.
//   MODE 0: out bf16 head-split [b,h,s,dk], value (acc+bias)*scale
//   MODE 1: out f32 [m][n], value acc+bias
//   MODE 2: out bf16 V^T [b,h,dk,s], value acc+bias
// ---------------------------------------------------------------------------
template <int MODE>
__global__ __launch_bounds__(256) void gemm_kernel(const u16* __restrict__ A,
                                                   const u16* __restrict__ Bt,
                                                   const float* __restrict__ bias,
                                                   void* __restrict__ Out,
                                                   float scale) {
    __shared__ __attribute__((aligned(16))) u16 As[128 * 32];
    __shared__ __attribute__((aligned(16))) u16 Bs[128 * 32];
    const int tid = threadIdx.x;
    const int wave = tid >> 6, lane = tid & 63;
    const int quad = lane >> 4, l15 = lane & 15;
    const int m0 = blockIdx.x * 128, n0 = blockIdx.y * 128;
    const int wm = (wave >> 1) * 64, wn = (wave & 1) * 64;
    const int rr = lane >> 2, cc = (lane & 3) * 8;

    const u16* Ag = A + (size_t)(m0 + wave * 32 + rr) * Kg + cc;
    const u16* Bg = Bt + (size_t)(n0 + wave * 32 + rr) * Kg + cc;
    u16* Asw = &As[wave * 32 * 32];
    u16* Bsw = &Bs[wave * 32 * 32];

    f32x4 acc[4][4] = {};

    for (int k0 = 0; k0 < Kg; k0 += 32) {
        __syncthreads();
        gll16(Ag + k0, Asw);
        gll16(Ag + k0 + (size_t)16 * Kg, Asw + 16 * 32);
        gll16(Bg + k0, Bsw);
        gll16(Bg + k0 + (size_t)16 * Kg, Bsw + 16 * 32);
        __syncthreads();

        bf16x8 a[4], b[4];
        for (int i = 0; i < 4; ++i)
            a[i] = *(const bf16x8*)(&As[(wm + i * 16 + l15) * 32 + quad * 8]);
        for (int j = 0; j < 4; ++j)
            b[j] = *(const bf16x8*)(&Bs[(wn + j * 16 + l15) * 32 + quad * 8]);
        for (int i = 0; i < 4; ++i)
            for (int j = 0; j < 4; ++j)
                acc[i][j] = __builtin_amdgcn_mfma_f32_16x16x32_bf16(a[i], b[j], acc[i][j], 0, 0, 0);
    }

    for (int i = 0; i < 4; ++i) {
        for (int j = 0; j < 4; ++j) {
            int col = n0 + wn + j * 16 + l15;
            float bv = bias[col];
            if (MODE == 0) {
                int h = col >> 6, dk = col & 63;
                for (int r = 0; r < 4; ++r) {
                    int row = m0 + wm + i * 16 + quad * 4 + r;
                    int bb = row >> 11, s = row & 2047;
                    ((u16*)Out)[((((size_t)bb * Hh + h) * Ss) + s) * DKk + dk] =
                        f2b((acc[i][j][r] + bv) * scale);
                }
            } else if (MODE == 2) {
                int h = col >> 6, dk = col & 63;
                int row0 = m0 + wm + i * 16 + quad * 4;
                int bb = row0 >> 11, s0 = row0 & 2047;
                u16x4 pk;
                for (int r = 0; r < 4; ++r) pk[r] = f2b(acc[i][j][r] + bv);
                *(u16x4*)((u16*)Out + (((size_t)bb * Hh + h) * DKk + dk) * Ss + s0) = pk;
            } else {
                for (int r = 0; r < 4; ++r) {
                    int row = m0 + wm + i * 16 + quad * 4 + r;
                    ((float*)Out)[(size_t)row * Ng + col] = acc[i][j][r] + bv;
                }
            }
        }
    }
}

// ---------------------------------------------------------------------------
// Causal flash attention. Q pre-scaled by 0.125*log2(e) (exp2 domain).
// Q,K bf16 [b,h,s,dk]; V^T bf16 [b,h,dk,s]. Block = 64 Q-rows x (b,h),
// 4 waves x 16 rows. LDS tiles are [2 chunks][64 rows][32] unpadded
// (global_load_lds lane-contiguous; stride-32 reads are 2-way = free).
// Heavy Q-tiles dispatched first. Out bf16 [b,s,h,dk].
// ---------------------------------------------------------------------------
__global__ __launch_bounds__(256) void attn_kernel(const u16* __restrict__ Qw,
                                                   const u16* __restrict__ Kw,
                                                   const u16* __restrict__ Vt,
                                                   u16* __restrict__ Ow) {
    __shared__ __attribute__((aligned(16))) u16 Qs[2 * 64 * 32];
    __shared__ __attribute__((aligned(16))) u16 Ks[2 * 64 * 32];
    __shared__ __attribute__((aligned(16))) u16 Vs[2 * 64 * 32];
    __shared__ __attribute__((aligned(16))) u16 Ps[4 * 16 * 72];

    const int idx = blockIdx.x;
    const int qt = (Ss / 64 - 1) - (idx >> 6);   // heavy tiles first
    const int bh = idx & 63;
    const int q0 = qt * 64;
    const int tid = threadIdx.x, wave = tid >> 6, lane = tid & 63;
    const int quad = lane >> 4, l15 = lane & 15;
    const int rr = lane >> 2, cc = (lane & 3) * 8;

    const u16* Qb = Qw + (size_t)bh * Ss * DKk;
    const u16* Kb = Kw + (size_t)bh * Ss * DKk;
    const u16* Vb = Vt + (size_t)bh * DKk * Ss;

    // stage Q once: chunk kc = dk 32-slice
    for (int kc = 0; kc < 2; ++kc)
        gll16(Qb + (size_t)(q0 + wave * 16 + rr) * DKk + kc * 32 + cc,
              &Qs[kc * 2048 + wave * 16 * 32]);
    __syncthreads();
    bf16x8 aq0 = *(const bf16x8*)(&Qs[(wave * 16 + l15) * 32 + quad * 8]);
    bf16x8 aq1 = *(const bf16x8*)(&Qs[2048 + (wave * 16 + l15) * 32 + quad * 8]);

    f32x4 acc_o[4] = {};
    float m_r[4], l_r[4];
    int rowg[4];
    for (int r = 0; r < 4; ++r) {
        m_r[r] = -1e30f; l_r[r] = 0.f;
        rowg[r] = q0 + wave * 16 + quad * 4 + r;
    }
    u16* Pw = &Ps[wave * 16 * 72];

    for (int j = 0; j <= qt; ++j) {
        __syncthreads();
        for (int c = 0; c < 2; ++c) {
            gll16(Kb + (size_t)(j * 64 + wave * 16 + rr) * DKk + c * 32 + cc,
                  &Ks[c * 2048 + wave * 16 * 32]);
            gll16(Vb + (size_t)(wave * 16 + rr) * Ss + j * 64 + c * 32 + cc,
                  &Vs[c * 2048 + wave * 16 * 32]);
        }
        __syncthreads();

        // S = Q K^T (already in exp2 domain)
        f32x4 sacc[4];
        for (int ct = 0; ct < 4; ++ct) {
            bf16x8 bk0 = *(const bf16x8*)(&Ks[(ct * 16 + l15) * 32 + quad * 8]);
            bf16x8 bk1 = *(const bf16x8*)(&Ks[2048 + (ct * 16 + l15) * 32 + quad * 8]);
            f32x4 z = {};
            z = __builtin_amdgcn_mfma_f32_16x16x32_bf16(aq0, bk0, z, 0, 0, 0);
            z = __builtin_amdgcn_mfma_f32_16x16x32_bf16(aq1, bk1, z, 0, 0, 0);
            sacc[ct] = z;
        }

        if (j == qt) {   // mask only the diagonal block
            for (int ct = 0; ct < 4; ++ct) {
                int ck = j * 64 + ct * 16 + l15;
                for (int r = 0; r < 4; ++r)
                    if (ck > rowg[r]) sacc[ct][r] = -1e30f;
            }
        }

        float mnew[4], alpha[4];
        for (int r = 0; r < 4; ++r) {
            float mx = fmaxf(fmaxf(sacc[0][r], sacc[1][r]), fmaxf(sacc[2][r], sacc[3][r]));
            for (int off = 1; off < 16; off <<= 1)
                mx = fmaxf(mx, __shfl_xor(mx, off, 64));
            mnew[r] = fmaxf(m_r[r], mx);
        }
        for (int r = 0; r < 4; ++r) {
            alpha[r] = EXP2(m_r[r] - mnew[r]);
            float sum = 0.f;
            for (int ct = 0; ct < 4; ++ct) {
                float p = EXP2(sacc[ct][r] - mnew[r]);
                sacc[ct][r] = p;
                sum += p;
            }
            for (int off = 1; off < 16; off <<= 1)
                sum += __shfl_xor(sum, off, 64);
            l_r[r] = l_r[r] * alpha[r] + sum;
            m_r[r] = mnew[r];
        }
        for (int dt = 0; dt < 4; ++dt)
            for (int r = 0; r < 4; ++r) acc_o[dt][r] *= alpha[r];

        // P C-layout -> per-wave LDS -> A-layout
        for (int ct = 0; ct < 4; ++ct)
            for (int r = 0; r < 4; ++r)
                Pw[(quad * 4 + r) * 72 + ct * 16 + l15] = f2b(sacc[ct][r]);

        for (int sc = 0; sc < 2; ++sc) {
            bf16x8 ap = *(const bf16x8*)(&Pw[l15 * 72 + sc * 32 + quad * 8]);
            for (int dt = 0; dt < 4; ++dt) {
                bf16x8 bv = *(const bf16x8*)(&Vs[sc * 2048 + (dt * 16 + l15) * 32 + quad * 8]);
                acc_o[dt] = __builtin_amdgcn_mfma_f32_16x16x32_bf16(ap, bv, acc_o[dt], 0, 0, 0);
            }
        }
    }

    const int b = bh >> 4, h = bh & 15;
    for (int r = 0; r < 4; ++r) {
        float inv = 1.f / l_r[r];
        int s = q0 + wave * 16 + quad * 4 + r;
        for (int dt = 0; dt < 4; ++dt) {
            int dk = dt * 16 + l15;
            Ow[(((size_t)b * Ss + s) * Hh + h) * DKk + dk] = f2b(acc_o[dt][r] * inv);
        }
    }
}

// ---------------------------------------------------------------------------
extern "C" void kernel_launch(void* const* d_in, const int* in_sizes, int n_in,
                              void* d_out, int out_size, void* d_ws, size_t ws_size,
                              hipStream_t stream) {
    // inputs: 0=x 1=q 2=k 3=v 4=mask 5=wq 6=bq 7=wk 8=bk 9=wv 10=bv 11=wo 12=bo
    const float* q  = (const float*)d_in[1];
    const float* k  = (const float*)d_in[2];
    const float* v  = (const float*)d_in[3];
    const float* wq = (const float*)d_in[5];
    const float* bq = (const float*)d_in[6];
    const float* wk = (const float*)d_in[7];
    const float* bk = (const float*)d_in[8];
    const float* wv = (const float*)d_in[9];
    const float* bv = (const float*)d_in[10];
    const float* wo = (const float*)d_in[11];
    const float* bo = (const float*)d_in[12];
    float* out = (float*)d_out;

    // workspace (u16 units), 104 MB total:
    u16* WqT = (u16*)d_ws;                   // 1M
    u16* WkT = WqT + 1024 * 1024;
    u16* WvT = WkT + 1024 * 1024;
    u16* WoT = WvT + 1024 * 1024;
    u16* Qc  = WoT + 1024 * 1024;            // 8M each (bf16 inputs)
    u16* Kc  = Qc + (size_t)Mg * Kg;
    u16* Vc  = Kc + (size_t)Mg * Kg;
    u16* Qw  = Vc + (size_t)Mg * Kg;         // projected
    u16* Kw  = Qw + (size_t)Mg * Kg;
    u16* VwT = Kw + (size_t)Mg * Kg;         // V^T [b,h,dk,s]
    u16* Ow  = Qc;                           // reuse Qc after attention inputs ready

    conv3_kernel<<<dim3(3 * (Mg * Kg / 8) / 256), 256, 0, stream>>>(q, k, v, Qc, Kc, Vc);
    wt4_kernel<<<dim3(16, 16, 4), 256, 0, stream>>>(wq, wk, wv, wo, WqT, WkT, WvT, WoT);

    dim3 gg(Mg / 128, Ng / 128);
    const float qscale = 0.125f * 1.44269504f;   // 1/sqrt(64) * log2(e)
    gemm_kernel<0><<<gg, 256, 0, stream>>>(Qc, WqT, bq, Qw, qscale);
    gemm_kernel<0><<<gg, 256, 0, stream>>>(Kc, WkT, bk, Kw, 1.0f);
    gemm_kernel<2><<<gg, 256, 0, stream>>>(Vc, WvT, bv, VwT, 1.0f);

    attn_kernel<<<dim3(2048), 256, 0, stream>>>(Qw, Kw, VwT, Ow);

    gemm_kernel<1><<<gg, 256, 0, stream>>>(Ow, WoT, bo, out, 1.0f);
}

// Round 3
// 363.873 us; speedup vs baseline: 1.8389x; 1.1179x over previous
//
#include <hip/hip_runtime.h>

typedef unsigned short u16;
typedef __bf16 bf16x8 __attribute__((ext_vector_type(8)));
typedef float f32x4 __attribute__((ext_vector_type(4)));
typedef u16 u16x8 __attribute__((ext_vector_type(8)));
typedef u16 u16x4 __attribute__((ext_vector_type(4)));

static constexpr int Bb = 4, Ss = 2048, Dd = 1024, Hh = 16, DKk = 64;
static constexpr int Mg = Bb * Ss;   // 8192
static constexpr int Kg = Dd;        // 1024
static constexpr int Ng = Dd;        // 1024

#if __has_builtin(__builtin_amdgcn_exp2f)
#define EXP2 __builtin_amdgcn_exp2f
#else
#define EXP2 exp2f
#endif

__device__ __forceinline__ u16 f2b(float f) {
    union { __bf16 h; u16 u; } c; c.h = (__bf16)f; return c.u;
}

typedef const __attribute__((address_space(1))) void gas_t;
typedef __attribute__((address_space(3))) void las_t;
__device__ __forceinline__ void gll16(const void* g, void* l) {
    __builtin_amdgcn_global_load_lds((gas_t*)g, (las_t*)l, 16, 0, 0);
}

// ---------------------------------------------------------------------------
// f32 -> bf16 convert for q,k,v (one fused launch). 8 elems / thread.
// ---------------------------------------------------------------------------
__global__ __launch_bounds__(256) void conv3_kernel(const float* __restrict__ q,
                                                    const float* __restrict__ k,
                                                    const float* __restrict__ v,
                                                    u16* __restrict__ oq,
                                                    u16* __restrict__ ok,
                                                    u16* __restrict__ ov) {
    const size_t per = (size_t)Mg * Kg / 8;
    size_t id = (size_t)blockIdx.x * 256 + threadIdx.x;
    size_t t = id / per, off = (id % per) * 8;
    const float* src = (t == 0) ? q : (t == 1) ? k : v;
    u16* dst = (t == 0) ? oq : (t == 1) ? ok : ov;
    float4 a = *(const float4*)(src + off);
    float4 b = *(const float4*)(src + off + 4);
    u16x8 o;
    o[0] = f2b(a.x); o[1] = f2b(a.y); o[2] = f2b(a.z); o[3] = f2b(a.w);
    o[4] = f2b(b.x); o[5] = f2b(b.y); o[6] = f2b(b.z); o[7] = f2b(b.w);
    *(u16x8*)(dst + off) = o;
}

// ---------------------------------------------------------------------------
// Weight transpose+convert: 4 weights in one launch (blockIdx.z selects).
// ---------------------------------------------------------------------------
__global__ __launch_bounds__(256) void wt4_kernel(const float* w0, const float* w1,
                                                  const float* w2, const float* w3,
                                                  u16* t0, u16* t1, u16* t2, u16* t3) {
    const float* W; u16* Wt;
    switch (blockIdx.z) {
        case 0: W = w0; Wt = t0; break;
        case 1: W = w1; Wt = t1; break;
        case 2: W = w2; Wt = t2; break;
        default: W = w3; Wt = t3; break;
    }
    __shared__ __attribute__((aligned(16))) u16 T[64 * 72];
    const int k0 = blockIdx.x * 64, n0 = blockIdx.y * 64;
    const int tid = threadIdx.x;
    for (int i = 0; i < 4; ++i) {
        int flat = tid + i * 256;
        int r = flat >> 4, c4 = flat & 15;
        float4 w4 = *(const float4*)(W + (size_t)(k0 + r) * 1024 + n0 + c4 * 4);
        u16* d = &T[r * 72 + c4 * 4];
        d[0] = f2b(w4.x); d[1] = f2b(w4.y); d[2] = f2b(w4.z); d[3] = f2b(w4.w);
    }
    __syncthreads();
    for (int i = 0; i < 2; ++i) {
        int flat = tid + i * 256;
        int n = flat >> 3, c8 = flat & 7;
        u16x8 v;
        for (int jj = 0; jj < 8; ++jj) v[jj] = T[(c8 * 8 + jj) * 72 + n];
        *(u16x8*)(Wt + (size_t)(n0 + n) * 1024 + k0 + c8 * 8) = v;
    }
}

// ---------------------------------------------------------------------------
// GEMM (m97-style): C[8192][1024] = A@B + bias.  A bf16 [m][k], Bt bf16 [n][k].
//   MODE 0: out bf16 head-split [b,h,s,dk], value (acc+bias)*scale
//   MODE 1: out f32 [m][n], value acc+bias
//   MODE 2: out bf16 V^T [b,h,dk,s], value acc+bias
// ---------------------------------------------------------------------------
template <int MODE>
__global__ __launch_bounds__(256) void gemm_kernel(const u16* __restrict__ A,
                                                   const u16* __restrict__ Bt,
                                                   const float* __restrict__ bias,
                                                   void* __restrict__ Out,
                                                   float scale) {
    __shared__ __attribute__((aligned(16))) u16 As[128 * 32];
    __shared__ __attribute__((aligned(16))) u16 Bs[128 * 32];
    const int tid = threadIdx.x;
    const int wave = tid >> 6, lane = tid & 63;
    const int quad = lane >> 4, l15 = lane & 15;
    const int m0 = blockIdx.x * 128, n0 = blockIdx.y * 128;
    const int wm = (wave >> 1) * 64, wn = (wave & 1) * 64;
    const int rr = lane >> 2, cc = (lane & 3) * 8;

    const u16* Ag = A + (size_t)(m0 + wave * 32 + rr) * Kg + cc;
    const u16* Bg = Bt + (size_t)(n0 + wave * 32 + rr) * Kg + cc;
    u16* Asw = &As[wave * 32 * 32];
    u16* Bsw = &Bs[wave * 32 * 32];

    f32x4 acc[4][4] = {};

    for (int k0 = 0; k0 < Kg; k0 += 32) {
        __syncthreads();
        gll16(Ag + k0, Asw);
        gll16(Ag + k0 + (size_t)16 * Kg, Asw + 16 * 32);
        gll16(Bg + k0, Bsw);
        gll16(Bg + k0 + (size_t)16 * Kg, Bsw + 16 * 32);
        __syncthreads();

        bf16x8 a[4], b[4];
        for (int i = 0; i < 4; ++i)
            a[i] = *(const bf16x8*)(&As[(wm + i * 16 + l15) * 32 + quad * 8]);
        for (int j = 0; j < 4; ++j)
            b[j] = *(const bf16x8*)(&Bs[(wn + j * 16 + l15) * 32 + quad * 8]);
        for (int i = 0; i < 4; ++i)
            for (int j = 0; j < 4; ++j)
                acc[i][j] = __builtin_amdgcn_mfma_f32_16x16x32_bf16(a[i], b[j], acc[i][j], 0, 0, 0);
    }

    for (int i = 0; i < 4; ++i) {
        for (int j = 0; j < 4; ++j) {
            int col = n0 + wn + j * 16 + l15;
            float bv = bias[col];
            if (MODE == 0) {
                int h = col >> 6, dk = col & 63;
                for (int r = 0; r < 4; ++r) {
                    int row = m0 + wm + i * 16 + quad * 4 + r;
                    int bb = row >> 11, s = row & 2047;
                    ((u16*)Out)[((((size_t)bb * Hh + h) * Ss) + s) * DKk + dk] =
                        f2b((acc[i][j][r] + bv) * scale);
                }
            } else if (MODE == 2) {
                int h = col >> 6, dk = col & 63;
                int row0 = m0 + wm + i * 16 + quad * 4;
                int bb = row0 >> 11, s0 = row0 & 2047;
                u16x4 pk;
                for (int r = 0; r < 4; ++r) pk[r] = f2b(acc[i][j][r] + bv);
                *(u16x4*)((u16*)Out + (((size_t)bb * Hh + h) * DKk + dk) * Ss + s0) = pk;
            } else {
                for (int r = 0; r < 4; ++r) {
                    int row = m0 + wm + i * 16 + quad * 4 + r;
                    ((float*)Out)[(size_t)row * Ng + col] = acc[i][j][r] + bv;
                }
            }
        }
    }
}

// ---------------------------------------------------------------------------
// Causal flash attention, S^T orientation. Q pre-scaled by 0.125*log2(e).
// Q,K bf16 [b,h,s,dk]; V^T bf16 [b,h,dk,s]. Block = 64 Q-rows x (b,h).
// S^T = K*Q^T so C-layout cols = q-rows: softmax stats are per-lane scalars
// (qrow = l15, replicated over the 4 quads -> 2 shuffles to reduce).
// P^T lands in [qrow][key] layout: vector ds_write_b64, contiguous b128 reads.
// PV computed as O^T = V^T * P; output written as u16x4 packs.
// ---------------------------------------------------------------------------
__global__ __launch_bounds__(256) void attn_kernel(const u16* __restrict__ Qw,
                                                   const u16* __restrict__ Kw,
                                                   const u16* __restrict__ Vt,
                                                   u16* __restrict__ Ow) {
    // QPs: Q staging (4096 u16) overlaid with P buffer (4*16*72 = 4608 u16)
    __shared__ __attribute__((aligned(16))) u16 QPs[4608];
    __shared__ __attribute__((aligned(16))) u16 Ks[2 * 64 * 32];
    __shared__ __attribute__((aligned(16))) u16 Vs[2 * 64 * 32];

    const int idx = blockIdx.x;
    const int qt = (Ss / 64 - 1) - (idx >> 6);   // heavy tiles first
    const int bh = idx & 63;
    const int q0 = qt * 64;
    const int tid = threadIdx.x, wave = tid >> 6, lane = tid & 63;
    const int quad = lane >> 4, l15 = lane & 15;
    const int rr = lane >> 2, cc = (lane & 3) * 8;

    const u16* Qb = Qw + (size_t)bh * Ss * DKk;
    const u16* Kb = Kw + (size_t)bh * Ss * DKk;
    const u16* Vb = Vt + (size_t)bh * DKk * Ss;

    for (int kc = 0; kc < 2; ++kc)
        gll16(Qb + (size_t)(q0 + wave * 16 + rr) * DKk + kc * 32 + cc,
              &QPs[kc * 2048 + wave * 16 * 32]);
    __syncthreads();
    bf16x8 aq0 = *(const bf16x8*)(&QPs[(wave * 16 + l15) * 32 + quad * 8]);
    bf16x8 aq1 = *(const bf16x8*)(&QPs[2048 + (wave * 16 + l15) * 32 + quad * 8]);

    f32x4 acc_o[4] = {};
    float m_r = -1e30f, l_r = 0.f;
    const int qrow = q0 + wave * 16 + l15;       // this lane's q-row
    u16* Pw = &QPs[wave * 16 * 72];

    for (int j = 0; j <= qt; ++j) {
        __syncthreads();
        for (int c = 0; c < 2; ++c) {
            gll16(Kb + (size_t)(j * 64 + wave * 16 + rr) * DKk + c * 32 + cc,
                  &Ks[c * 2048 + wave * 16 * 32]);
            gll16(Vb + (size_t)(wave * 16 + rr) * Ss + j * 64 + c * 32 + cc,
                  &Vs[c * 2048 + wave * 16 * 32]);
        }
        __syncthreads();

        // S^T = K Q^T: rows = keys, cols = q-rows (exp2 domain)
        f32x4 sacc[4];
        for (int ct = 0; ct < 4; ++ct) {
            bf16x8 bk0 = *(const bf16x8*)(&Ks[(ct * 16 + l15) * 32 + quad * 8]);
            bf16x8 bk1 = *(const bf16x8*)(&Ks[2048 + (ct * 16 + l15) * 32 + quad * 8]);
            f32x4 z = {};
            z = __builtin_amdgcn_mfma_f32_16x16x32_bf16(bk0, aq0, z, 0, 0, 0);
            z = __builtin_amdgcn_mfma_f32_16x16x32_bf16(bk1, aq1, z, 0, 0, 0);
            sacc[ct] = z;
        }

        if (j == qt) {   // diagonal block: mask keys > qrow
            for (int ct = 0; ct < 4; ++ct) {
                int kbase = j * 64 + ct * 16 + quad * 4;
                for (int r = 0; r < 4; ++r)
                    if (kbase + r > qrow) sacc[ct][r] = -1e30f;
            }
        }

        // per-lane softmax stats (all 16 values belong to qrow = l15)
        float mx = sacc[0][0];
        for (int ct = 0; ct < 4; ++ct)
            for (int r = 0; r < 4; ++r) mx = fmaxf(mx, sacc[ct][r]);
        mx = fmaxf(mx, __shfl_xor(mx, 16, 64));
        mx = fmaxf(mx, __shfl_xor(mx, 32, 64));
        float mnew = fmaxf(m_r, mx);

        float sum = 0.f;
        for (int ct = 0; ct < 4; ++ct)
            for (int r = 0; r < 4; ++r) {
                float p = EXP2(sacc[ct][r] - mnew);
                sacc[ct][r] = p;
                sum += p;
            }
        sum += __shfl_xor(sum, 16, 64);
        sum += __shfl_xor(sum, 32, 64);

        bool renorm = mnew > m_r;
        float alpha = renorm ? EXP2(m_r - mnew) : 1.0f;
        l_r = l_r * alpha + sum;
        m_r = mnew;
        if (__any(renorm && m_r > -1e29f)) {
            for (int dt = 0; dt < 4; ++dt)
                for (int r = 0; r < 4; ++r) acc_o[dt][r] *= alpha;
        }

        // P^T -> per-wave LDS [qrow][key], vectorized b64 writes
        for (int ct = 0; ct < 4; ++ct) {
            u16x4 pk;
            for (int r = 0; r < 4; ++r) pk[r] = f2b(sacc[ct][r]);
            *(u16x4*)(&Pw[l15 * 72 + ct * 16 + quad * 4]) = pk;
        }

        // O^T += V^T * P
        for (int sc = 0; sc < 2; ++sc) {
            bf16x8 ap = *(const bf16x8*)(&Pw[l15 * 72 + sc * 32 + quad * 8]);
            for (int dt = 0; dt < 4; ++dt) {
                bf16x8 bv = *(const bf16x8*)(&Vs[sc * 2048 + (dt * 16 + l15) * 32 + quad * 8]);
                acc_o[dt] = __builtin_amdgcn_mfma_f32_16x16x32_bf16(bv, ap, acc_o[dt], 0, 0, 0);
            }
        }
    }

    // O[s][dk]: lane holds O^T[d = dt*16+quad*4+r][qrow = l15]
    const int b = bh >> 4, h = bh & 15;
    const float inv = 1.f / l_r;
    const int s = q0 + wave * 16 + l15;
    u16* orow = Ow + (((size_t)b * Ss + s) * Hh + h) * DKk;
    for (int dt = 0; dt < 4; ++dt) {
        u16x4 pk;
        for (int r = 0; r < 4; ++r) pk[r] = f2b(acc_o[dt][r] * inv);
        *(u16x4*)(orow + dt * 16 + quad * 4) = pk;
    }
}

// ---------------------------------------------------------------------------
extern "C" void kernel_launch(void* const* d_in, const int* in_sizes, int n_in,
                              void* d_out, int out_size, void* d_ws, size_t ws_size,
                              hipStream_t stream) {
    const float* q  = (const float*)d_in[1];
    const float* k  = (const float*)d_in[2];
    const float* v  = (const float*)d_in[3];
    const float* wq = (const float*)d_in[5];
    const float* bq = (const float*)d_in[6];
    const float* wk = (const float*)d_in[7];
    const float* bk = (const float*)d_in[8];
    const float* wv = (const float*)d_in[9];
    const float* bv = (const float*)d_in[10];
    const float* wo = (const float*)d_in[11];
    const float* bo = (const float*)d_in[12];
    float* out = (float*)d_out;

    u16* WqT = (u16*)d_ws;
    u16* WkT = WqT + 1024 * 1024;
    u16* WvT = WkT + 1024 * 1024;
    u16* WoT = WvT + 1024 * 1024;
    u16* Qc  = WoT + 1024 * 1024;
    u16* Kc  = Qc + (size_t)Mg * Kg;
    u16* Vc  = Kc + (size_t)Mg * Kg;
    u16* Qw  = Vc + (size_t)Mg * Kg;
    u16* Kw  = Qw + (size_t)Mg * Kg;
    u16* VwT = Kw + (size_t)Mg * Kg;
    u16* Ow  = Qc;   // reuse

    conv3_kernel<<<dim3(3 * (Mg * Kg / 8) / 256), 256, 0, stream>>>(q, k, v, Qc, Kc, Vc);
    wt4_kernel<<<dim3(16, 16, 4), 256, 0, stream>>>(wq, wk, wv, wo, WqT, WkT, WvT, WoT);

    dim3 gg(Mg / 128, Ng / 128);
    const float qscale = 0.125f * 1.44269504f;
    gemm_kernel<0><<<gg, 256, 0, stream>>>(Qc, WqT, bq, Qw, qscale);
    gemm_kernel<0><<<gg, 256, 0, stream>>>(Kc, WkT, bk, Kw, 1.0f);
    gemm_kernel<2><<<gg, 256, 0, stream>>>(Vc, WvT, bv, VwT, 1.0f);

    attn_kernel<<<dim3(2048), 256, 0, stream>>>(Qw, Kw, VwT, Ow);

    gemm_kernel<1><<<gg, 256, 0, stream>>>(Ow, WoT, bo, out, 1.0f);
}